// Round 4
// baseline (101.813 us; speedup 1.0000x reference)
//
#include <hip/hip_runtime.h>
#include <math.h>

// ROI adaptive max-pool to 7x7 (torch adaptive_max_pool2d bin semantics).
// feature_map: [B=2, C=256, H=50, W=50] fp32
// rois:        [R=192, 5] int32 (batch, x1, y1, x2, y2), 1<=w,h, x2<=W, y2<=H
// out:         [R, C, 7, 7] fp32
//
// Round 8: layout fix. Previous structure (lane=column) wasted ~78% of lanes
// (w_avg~13.5 of 64) and drowned in per-wave bin bookkeeping (R7 regression
// proved VALU/issue-bound, not load-count-bound). New structure:
//   K1: transpose fm -> fm_t[B][H][W][C] in d_ws (LDS-tiled, L2-resident).
//   K2: block=(roi, row-bin i), thread=channel. 100% lane utilization,
//       every load = 256B coalesced (64 consecutive channels), bin math
//       wave-uniform once per block, no LDS/syncthreads in the pool kernel.
//       bid = i*R + r keeps all 7 bins of a ROI on one XCD (192 % 8 == 0).

#define OUT_N 7
#define B_    2
#define C_    256
#define H_    50
#define W_    50
#define PLANE (H_ * W_)        // 2500
#define TLDSW 66               // [x][cc] tile: 64 cc + 2 pad (2-way = free)

// ---- Kernel 1: fm [B][C][H][W] -> fm_t [B][H][W][C] -------------------
// Block = (b, y, cgroup of 64). Read: 50-float coalesced runs. LDS turn.
// Write: 256B fully coalesced along c.
__global__ __launch_bounds__(256) void transpose_kernel(
    const float* __restrict__ fm, float* __restrict__ fm_t)
{
    __shared__ float tile[H_ * TLDSW];          // 13.2 KB

    const int t   = threadIdx.x;
    const int bid = blockIdx.x;                 // 0..399
    const int cg  = bid & 3;                    // channel group of 64
    const int yy  = bid >> 2;
    const int y   = yy % H_;
    const int b   = yy / H_;

    const float* src = fm + (size_t)(b * C_ + cg * 64) * PLANE + y * W_;
    #pragma unroll
    for (int k = 0; k < 13; ++k) {              // 64*50 = 3200 elements
        const int e = k * 256 + t;
        if (e < 64 * W_) {
            const int cc = e / W_;              // magic-mul (const 50)
            const int x  = e - cc * W_;
            tile[x * TLDSW + cc] = src[cc * PLANE + x];
        }
    }
    __syncthreads();

    float* dst = fm_t + ((size_t)(b * H_ + y) * W_) * C_ + cg * 64;
    #pragma unroll
    for (int k = 0; k < 13; ++k) {
        const int e = k * 256 + t;
        if (e < 64 * W_) {
            const int x  = e >> 6;              // 0..49
            const int cc = e & 63;
            dst[x * C_ + cc] = tile[x * TLDSW + cc];   // 256B coalesced
        }
    }
}

// ---- Kernel 2: pool from fm_t ------------------------------------------
// Block = (roi r, row-bin i); thread = channel c. All bin bounds are
// wave-uniform; acc[7]/xs[7]/xe[7] fully unrolled -> static reg indexing.
__global__ __launch_bounds__(256) void pool_kernel(
    const float* __restrict__ fm_t, const int* __restrict__ rois,
    float* __restrict__ out, int R)
{
    const int bid = blockIdx.x;                 // i*R + r
    const int i   = bid / R;                    // runtime div, once per block
    const int r   = bid - i * R;
    const int c   = threadIdx.x;                // channel 0..255

    const int* roi = rois + r * 5;
    const int b  = roi[0];
    const int x1 = roi[1];
    const int y1 = roi[2];
    const int x2 = roi[3];
    const int y2 = roi[4];
    const int h  = y2 - y1;
    const int w  = x2 - x1;

    const int ys = y1 + (i * h) / OUT_N;
    const int ye = y1 + ((i + 1) * h + OUT_N - 1) / OUT_N;   // >= ys+1

    int xs[OUT_N], xe[OUT_N];
    #pragma unroll
    for (int j = 0; j < OUT_N; ++j) {
        xs[j] = x1 + (j * w) / OUT_N;
        xe[j] = x1 + ((j + 1) * w + OUT_N - 1) / OUT_N;      // >= xs[j]+1
    }

    float acc[OUT_N];
    #pragma unroll
    for (int j = 0; j < OUT_N; ++j) acc[j] = -INFINITY;

    const float* base = fm_t + ((size_t)(b * H_ + ys) * W_) * C_ + c;
    for (int y = ys; y < ye; ++y) {
        #pragma unroll
        for (int j = 0; j < OUT_N; ++j) {
            float a = acc[j];
            int x = xs[j];
            for (; x + 1 < xe[j]; x += 2) {     // 2 loads in flight
                const float v0 = base[x * C_];
                const float v1 = base[(x + 1) * C_];
                a = fmaxf(a, fmaxf(v0, v1));
            }
            if (x < xe[j]) a = fmaxf(a, base[x * C_]);
            acc[j] = a;
        }
        base += W_ * C_;
    }

    float* op = out + ((size_t)r * C_ + c) * (OUT_N * OUT_N) + i * OUT_N;
    #pragma unroll
    for (int j = 0; j < OUT_N; ++j) op[j] = acc[j];
}

extern "C" void kernel_launch(void* const* d_in, const int* in_sizes, int n_in,
                              void* d_out, int out_size, void* d_ws, size_t ws_size,
                              hipStream_t stream)
{
    const float* fm = (const float*)d_in[0];
    const int* rois = (const int*)d_in[1];
    float* out      = (float*)d_out;
    float* fm_t     = (float*)d_ws;             // 5.12 MB of 256 MiB ws

    const int R = in_sizes[1] / 5;              // 192

    transpose_kernel<<<B_ * H_ * 4, 256, 0, stream>>>(fm, fm_t);
    pool_kernel<<<OUT_N * R, 256, 0, stream>>>(fm_t, rois, out, R);
}

// Round 5
// 101.602 us; speedup vs baseline: 1.0021x; 1.0021x over previous
//
#include <hip/hip_runtime.h>
#include <math.h>

// ROI adaptive max-pool to 7x7 (torch adaptive_max_pool2d bin semantics).
// feature_map: [B=2, C=256, H=50, W=50] fp32
// rois:        [R=192, 5] int32 (batch, x1, y1, x2, y2), 1<=w,h, x2<=W, y2<=H
// out:         [R, C, 7, 7] fp32
//
// Round 9 = R5 (best measured: 74.8) + ONE change: kill the latency chain.
// R5's per-bin data-dependent while loop drained vmcnt every 2 rows
// (~15 serialized round trips/wave). A row-bin is bounded by 9 rows
// (ceil(50/7)+1, the reference's K), so each bin now issues a FIXED batch
// of 9 branch-free loads with row clamped to the bin end (duplicates are
// harmless under max and hit L1), then one wait + fmax tree. All 63 loads
// per wave are compile-time independent -> compiler pipelines across bins;
// serialized round trips ~15 -> ~3-4. No while, no carry, no per-row
// bookkeeping (the R7 mistake). d_ws is NOT used (R8 lesson: dirtying the
// workspace re-adds a ~41us 256MiB re-poison per iteration).
// Everything else identical to R5: float2 lanes (2ch/wave), CPB=8,
// 14.8KB LDS, grid 6144 with cg%8 XCD partitioning (640KB fm per XCD L2),
// LDS epilogue with coalesced output stores.

#define OUT_N 7
#define WPB 4                 // waves per block
#define CHW 2                 // channels per wave (float2 col-pair lanes)
#define CPB (WPB * CHW)       // 8 channels per block
#define LDSW 66               // 64 cols + 2 pad
#define KMAX 9                // max rows per row-bin: ceil(50/7)+1

__global__ __launch_bounds__(256, 6) void roicrop_kernel(
    const float* __restrict__ fm,
    const int* __restrict__ rois,
    float* __restrict__ out,
    int R, int C, int H, int W, int nfm)
{
    __shared__ float tw[CPB][OUT_N][LDSW];   // 14.8 KB

    const int lane = threadIdx.x & 63;
    const int wave = threadIdx.x >> 6;        // 0..3
    const int cg_per_r = C / CPB;             // 32
    const int r  = blockIdx.x / cg_per_r;
    const int cg = blockIdx.x - r * cg_per_r; // XCD = cg%8 -> 640KB fm/XCD

    const int csub = lane >> 5;               // channel within wave: 0..1
    const int l2   = lane & 31;               // float2 lane within channel
    const int c    = cg * CPB + wave * CHW + csub;
    const int wc   = wave * CHW + csub;       // channel-in-block

    const int* roi = rois + r * 5;
    const int b  = roi[0];
    const int x1 = roi[1];
    const int y1 = roi[2];
    const int x2 = roi[3];
    const int y2 = roi[4];
    const int h = y2 - y1;
    const int w = x2 - x1;

    // Lane covers absolute columns [x0+2*l2, x0+2*l2+1]; x0, W even => every
    // USED lane (dx < w) stays inside its row; unused lanes may run past the
    // row/plane but only the absolute buffer end is a hazard -> one clamp.
    const int x0 = x1 & ~1;
    const unsigned colb = (unsigned)(x0 + 2 * l2);
    const unsigned base = (unsigned)(b * C + c) * (unsigned)(H * W) + colb;
    const unsigned lim  = (unsigned)(nfm - 2);

    #pragma unroll
    for (int i = 0; i < OUT_N; ++i) {
        const int ys   = y1 + (i * h) / OUT_N;
        const int ye   = y1 + ((i + 1) * h + OUT_N - 1) / OUT_N;  // >= ys+1
        const int ymax = ye - 1;                                  // <= 49

        // Fixed batch of KMAX independent clamped loads (no branches, no
        // loop-carried deps) -> single vmcnt wait, deep MLP.
        float2 v[KMAX];
        #pragma unroll
        for (int k = 0; k < KMAX; ++k) {
            int row = ys + k;
            if (row > ymax) row = ymax;        // duplicate rows: max-neutral
            unsigned ia = base + (unsigned)(row * W);
            if (ia > lim) ia = lim;            // buffer-end safety only
            v[k] = *reinterpret_cast<const float2*>(fm + ia);
        }
        float2 m = v[0];
        #pragma unroll
        for (int k = 1; k < KMAX; ++k) {
            m.x = fmaxf(m.x, v[k].x);
            m.y = fmaxf(m.y, v[k].y);
        }

        *reinterpret_cast<float2*>(&tw[wc][i][2 * l2]) = m;  // ds_write_b64
    }
    __syncthreads();

    // Epilogue: CPB*49 = 392 outputs, 256 threads -> 2 rounds. Column bins
    // reduce from LDS (x0-based indexing, shifted by off = x1-x0).
    const int off = x1 - x0;
    float* obase = out + ((size_t)r * C + cg * CPB) * (OUT_N * OUT_N);
    for (int o = threadIdx.x; o < CPB * OUT_N * OUT_N; o += 256) {
        const int twc = o / (OUT_N * OUT_N);
        const int l   = o - twc * (OUT_N * OUT_N);
        const int i   = l / OUT_N;
        const int j   = l - i * OUT_N;
        const int xs  = (j * w) / OUT_N;
        const int xe  = ((j + 1) * w + OUT_N - 1) / OUT_N;
        float m2 = -INFINITY;
        for (int dx = xs; dx < xe; ++dx) {
            m2 = fmaxf(m2, tw[twc][i][off + dx]);
        }
        obase[o] = m2;                         // fully coalesced: offset == o
    }
}

extern "C" void kernel_launch(void* const* d_in, const int* in_sizes, int n_in,
                              void* d_out, int out_size, void* d_ws, size_t ws_size,
                              hipStream_t stream)
{
    const float* fm = (const float*)d_in[0];
    const int* rois = (const int*)d_in[1];
    float* out      = (float*)d_out;

    const int R = in_sizes[1] / 5;                        // 192
    const int C = out_size / (R * OUT_N * OUT_N);         // 256
    const int H = 50;
    const int W = 50;
    const int nfm = in_sizes[0];                          // B*C*H*W elements

    const int grid = R * (C / CPB);                       // 6144
    roicrop_kernel<<<grid, 256, 0, stream>>>(fm, rois, out, R, C, H, W, nfm);
}

// Round 6
// 73.735 us; speedup vs baseline: 1.3808x; 1.3779x over previous
//
#include <hip/hip_runtime.h>
#include <math.h>

// ROI adaptive max-pool to 7x7 (torch adaptive_max_pool2d bin semantics).
// feature_map: [B=2, C=256, H=50, W=50] fp32
// rois:        [R=192, 5] int32 (batch, x1, y1, x2, y2), 1<=w,h, x2<=W, y2<=H
// out:         [R, C, 7, 7] fp32
//
// Round 10. R9 profile (kernel 52us, HBM 3%, VALU 33%, occ 67%) => L1-path
// issue/latency bound; R9's 9-row fixed batches were 4.7x load redundancy.
// This round keeps deep memory-level parallelism but loads ~h+7 rows, not 63:
//  - k-outer/bin-inner: KB = max bin height (uniform, ~ceil(h/7)). Each k
//    issues 7 independent clamped loads (one per bin) -> 7 in flight,
//    ~3 vmcnt drains per wave, rows loaded = 7*KB ~= h+7.
//  - 4 channels/wave x 32 cols (float2 lanes): typical ROIs (off+w<=32) need
//    one pass -> half the waves and half the L1 traffic of 2ch x 64col;
//    wide ROIs take a second 32-col pass (wave-uniform branch).
//  - m[7]/v[7] only indexed from fully-unrolled loops (static reg indexing).
//  - no d_ws (R8: dirtying workspace re-adds a ~41us 256MiB re-poison).
// CPB=16, grid=R*16=3072, LDS 28.9KB -> 5 blocks/CU (20 waves).

#define OUT_N 7
#define WPB 4                 // waves per block
#define CHW 4                 // channels per wave
#define CPB (WPB * CHW)       // 16 channels per block
#define LDSW 66               // 64 col slots + 2 pad (even: float2 aligned)

__global__ __launch_bounds__(256, 5) void roicrop_kernel(
    const float* __restrict__ fm,
    const int* __restrict__ rois,
    float* __restrict__ out,
    int R, int C, int H, int W, int nfm)
{
    __shared__ float tw[CPB][OUT_N][LDSW];   // 28.9 KB

    const int lane = threadIdx.x & 63;
    const int wave = threadIdx.x >> 6;        // 0..3
    const int cg_per_r = C / CPB;             // 16
    const int r  = blockIdx.x / cg_per_r;
    const int cg = blockIdx.x - r * cg_per_r; // cg%8 spreads fm over XCD L2s

    const int csub = lane >> 4;               // channel within wave: 0..3
    const int l2   = lane & 15;               // float2 lane within channel
    const int c    = cg * CPB + wave * CHW + csub;
    const int wc   = wave * CHW + csub;       // channel-in-block

    const int* roi = rois + r * 5;
    const int b  = roi[0];
    const int x1 = roi[1];
    const int y1 = roi[2];
    const int x2 = roi[3];
    const int y2 = roi[4];
    const int h = y2 - y1;
    const int w = x2 - x1;

    // Lane covers absolute columns x0+32p+{2*l2, 2*l2+1}; x0,W even => used
    // lanes (slot < off+w) stay in-row; only hazard is the absolute buffer
    // end (last plane's trailing lanes) -> one index clamp, values unread.
    const int x0  = x1 & ~1;
    const int off = x1 - x0;                  // 0 or 1
    const unsigned base = (unsigned)(b * C + c) * (unsigned)(H * W)
                        + (unsigned)(x0 + 2 * l2);
    const unsigned lim  = (unsigned)(nfm - 2);

    // Row-bin bounds (wave-uniform). KB = max bin height: the k-loop trip
    // count. Clamped duplicate rows are max-neutral and L1-hot.
    int ys[OUT_N], ym[OUT_N];
    int KB = 1;
    #pragma unroll
    for (int i = 0; i < OUT_N; ++i) {
        ys[i] = y1 + (i * h) / OUT_N;
        const int ye = y1 + ((i + 1) * h + OUT_N - 1) / OUT_N;  // >= ys+1
        ym[i] = ye - 1;
        const int hb = ye - ys[i];
        KB = hb > KB ? hb : KB;
    }

    const int npass = (off + w > 32) ? 2 : 1; // wide ROIs: 2nd 32-col pass

    for (int p = 0; p < npass; ++p) {
        const unsigned pb = base + (unsigned)(32 * p);

        float2 m[OUT_N];
        #pragma unroll
        for (int i = 0; i < OUT_N; ++i) m[i] = make_float2(-INFINITY, -INFINITY);

        for (int k = 0; k < KB; ++k) {
            // 7 independent loads in flight (addresses independent of data).
            float2 v[OUT_N];
            #pragma unroll
            for (int i = 0; i < OUT_N; ++i) {
                int row = ys[i] + k;
                if (row > ym[i]) row = ym[i];      // dup rows: max-neutral
                unsigned ia = pb + (unsigned)(row * W);
                if (ia > lim) ia = lim;            // buffer-end safety only
                v[i] = *reinterpret_cast<const float2*>(fm + ia);
            }
            #pragma unroll
            for (int i = 0; i < OUT_N; ++i) {
                m[i].x = fmaxf(m[i].x, v[i].x);
                m[i].y = fmaxf(m[i].y, v[i].y);
            }
        }

        #pragma unroll
        for (int i = 0; i < OUT_N; ++i) {
            *reinterpret_cast<float2*>(&tw[wc][i][32 * p + 2 * l2]) = m[i];
        }
    }
    __syncthreads();

    // Epilogue: CPB*49 = 784 outputs, 256 threads -> ~3 rounds. Column bins
    // reduce from LDS (slots are x0-relative, shifted by off).
    float* obase = out + ((size_t)r * C + cg * CPB) * (OUT_N * OUT_N);
    for (int o = threadIdx.x; o < CPB * OUT_N * OUT_N; o += 256) {
        const int twc = o / (OUT_N * OUT_N);
        const int l   = o - twc * (OUT_N * OUT_N);
        const int i   = l / OUT_N;
        const int j   = l - i * OUT_N;
        const int xs  = (j * w) / OUT_N;
        const int xe  = ((j + 1) * w + OUT_N - 1) / OUT_N;
        float m2 = -INFINITY;
        for (int dx = xs; dx < xe; ++dx) {
            m2 = fmaxf(m2, tw[twc][i][off + dx]);
        }
        obase[o] = m2;                         // fully coalesced: offset == o
    }
}

extern "C" void kernel_launch(void* const* d_in, const int* in_sizes, int n_in,
                              void* d_out, int out_size, void* d_ws, size_t ws_size,
                              hipStream_t stream)
{
    const float* fm = (const float*)d_in[0];
    const int* rois = (const int*)d_in[1];
    float* out      = (float*)d_out;

    const int R = in_sizes[1] / 5;                        // 192
    const int C = out_size / (R * OUT_N * OUT_N);         // 256
    const int H = 50;
    const int W = 50;
    const int nfm = in_sizes[0];                          // B*C*H*W elements

    const int grid = R * (C / CPB);                       // 3072
    roicrop_kernel<<<grid, 256, 0, stream>>>(fm, rois, out, R, C, H, W, nfm);
}